// Round 7
// baseline (257.677 us; speedup 1.0000x reference)
//
#include <hip/hip_runtime.h>

#define K_CODES 4096
#define DIM 256
#define SEQ 2048
#define NTOK 65536

typedef __bf16 bf16x8 __attribute__((ext_vector_type(8)));
typedef float floatx4 __attribute__((ext_vector_type(4)));
typedef unsigned short u16x8 __attribute__((ext_vector_type(8)));

__device__ __forceinline__ unsigned short f2bf(float f) {
    union { float f; unsigned int u; } v; v.f = f;
    unsigned int u = v.u;
    unsigned int r = u + 0x7fffu + ((u >> 16) & 1u);   // RNE
    return (unsigned short)(r >> 16);
}

// async global->LDS, 16B per lane. LDS dest = wave-uniform base + lane*16.
__device__ __forceinline__ void async_cp16(const void* g, const void* lds_base) {
    typedef __attribute__((address_space(1))) const unsigned int guint;
    typedef __attribute__((address_space(3))) unsigned int luint;
    __builtin_amdgcn_global_load_lds(
        (guint*)(unsigned long long)g,
        (luint*)(unsigned int)(unsigned long long)lds_base,
        16, 0, 0);
}

// ---------------- kernel 1: swizzled bf16 codebook + biased norms -----------
// (round-6 verbatim)
// cb_swz[((gc*16 + ns*8 + ks)*64 + quad*16 + col)*8 + j]
//   = bf16(codebook[gc*32 + ns*16 + col][quad*8 + ks*32 + j])
// norms[row] = ||e||^2 + 0.25 (bias keeps dist positive for the packed key).
__global__ __launch_bounds__(256) void k_prep(const float* __restrict__ cb,
        unsigned short* __restrict__ cb_swz, float* __restrict__ norms,
        float* __restrict__ loss_slot) {
    const int c = blockIdx.x;
    const int t = threadIdx.x;
    const int row_loc = t >> 3;       // 0..31 code within chunk
    const int ks = t & 7;             // k-slice
    const int row = c * 32 + row_loc;
    const float* src = cb + (size_t)row * DIM + ks * 32;
    float vals[32];
    float s = 0.0f;
    #pragma unroll
    for (int i = 0; i < 8; ++i) {
        floatx4 v = *(const floatx4*)(src + i * 4);
        #pragma unroll
        for (int j = 0; j < 4; ++j) { vals[i * 4 + j] = v[j]; s += v[j] * v[j]; }
    }
    const int ns = row_loc >> 4, col = row_loc & 15;
    #pragma unroll
    for (int quad = 0; quad < 4; ++quad) {
        u16x8 p;
        #pragma unroll
        for (int j = 0; j < 8; ++j) p[j] = f2bf(vals[quad * 8 + j]);
        *(u16x8*)(cb_swz + ((size_t)((c * 16 + ns * 8 + ks) * 64 + quad * 16 + col)) * 8) = p;
    }
    s += __shfl_xor(s, 1); s += __shfl_xor(s, 2); s += __shfl_xor(s, 4);
    if (ks == 0) norms[row] = s + 0.25f;
    if (c == 0 && t == 0) *loss_slot = 0.0f;
}

// ---------------- kernel 2: MFMA distance GEMM + packed argmin --------------
// OCCUPANCY VARIANT: 128 tokens/block (2 M-tiles/wave), grid 1024 (h-split),
// af[2][8] = 64 AGPR -> ~150 regs/wave -> 3 waves/SIMD (vs 2 for the 256-token
// round-0 shape whose af[4][8]=128 AGPR caps it at 2). LDS 32.8 KB: the X
// staging buffer (16 KB, stride-256 + round-5-verified XOR swizzle) ALIASES
// ring[1], which is first written by the chunk-1 prefetch AFTER xs is dead.
// Loop body/schedule is round-0 verbatim (1 barrier/chunk, prefetch depth 1).
// All af indices literal (af0/af1) - rule-#20 spill tripwire avoided.
__global__ __launch_bounds__(256, 3) void k_argmin(const float* __restrict__ x,
        const unsigned short* __restrict__ cb_swz, const float* __restrict__ norms,
        unsigned int* __restrict__ halfmin, float* __restrict__ loss_slot) {
    __shared__ __align__(16) unsigned short ring[2][8192];   // 32768 B
    __shared__ float wpart[4];
    unsigned short* xs = ring[1];        // prologue-only alias: 32 tok x 256 d
    const int t = threadIdx.x;
    const int lane = t & 63, w = t >> 6;
    const int col = lane & 15, quad = lane >> 4;
    const int bx = blockIdx.x;
    const int h = bx & 1;                  // code half
    const int tb = (bx >> 1) * 128;        // first token of block
    const int b = tb >> 11, s0 = tb & 2047;
    const float* xin = x + (size_t)b * DIM * SEQ;

    // prefetch B chunk 0 of this half into ring[0] (overlaps X staging)
    {
        const char* src = (const char*)cb_swz + (size_t)h * 64 * 16384;
        #pragma unroll
        for (int i = 0; i < 4; ++i)
            async_cp16(src + i * 4096 + w * 1024 + lane * 16,
                       (char*)ring[0] + i * 4096 + w * 1024);
    }

    // ---- X staging: 4 phases x 32 tokens into xs(=ring[1]); wave p grabs its
    // two M-tiles in phase p. Element (tok,d) at
    //   xs[tok*256 + ((d>>3) ^ (tok>>2))*8 + (d&7)]
    // (XOR swizzle: staging writes hit all 32 banks, 2 lanes/bank = free;
    //  verified in round 5: conflicts 7.6M -> 295K, absmax identical).
    bf16x8 af0[8], af1[8];
    float a2 = 0.0f;
    const int q = t & 7, dgp = t >> 3, sq = q * 4;
    for (int p = 0; p < 4; ++p) {
        const int sbase = s0 + p * 32 + sq;
        #pragma unroll
        for (int i = 0; i < 8; ++i) {
            const int d = i * 32 + dgp;
            floatx4 v = *(const floatx4*)(xin + (size_t)d * SEQ + sbase);
            a2 += v[0]*v[0] + v[1]*v[1] + v[2]*v[2] + v[3]*v[3];
            const int chs = (d >> 3) ^ q;            // swizzled 16B chunk
            #pragma unroll
            for (int j = 0; j < 4; ++j)
                xs[(sq + j) * 256 + chs * 8 + (d & 7)] = f2bf(-2.0f * v[j]);
        }
        __syncthreads();
        if (w == p) {
            // rows col (af0) and 16+col (af1); swizzle key = row>>2 (= q of
            // staging since token = q*4+j). Literal af indices only.
            #pragma unroll
            for (int ks = 0; ks < 8; ++ks)
                af0[ks] = *(const bf16x8*)
                    &xs[col * 256 + (((quad + ks * 4) ^ (col >> 2)) * 8)];
            #pragma unroll
            for (int ks = 0; ks < 8; ++ks)
                af1[ks] = *(const bf16x8*)
                    &xs[(16 + col) * 256 + (((quad + ks * 4) ^ (4 + (col >> 2))) * 8)];
        }
        __syncthreads();
    }
    // block-reduce a2; h==0 blocks contribute ||x||^2 part of the loss
    #pragma unroll
    for (int off = 1; off < 64; off <<= 1) a2 += __shfl_xor(a2, off);
    if (lane == 0) wpart[w] = a2;
    __syncthreads();   // xs dead from here; ring[1] free for chunk-1 prefetch
    if (t == 0 && h == 0)
        atomicAdd(loss_slot,
                  (wpart[0] + wpart[1] + wpart[2] + wpart[3]) * (1.25f / 16777216.0f));

    unsigned int minkey0[4], minkey1[4];
    #pragma unroll
    for (int r = 0; r < 4; ++r) { minkey0[r] = 0xFFFFFFFFu; minkey1[r] = 0xFFFFFFFFu; }

    #pragma unroll 1
    for (int c = 0; c < 64; ++c) {
        __syncthreads();                       // ring[c&1] ready, readers of c-1 done
        if (c < 63) {
            const char* src = (const char*)cb_swz + (size_t)(h * 64 + c + 1) * 16384;
            char* dst = (char*)ring[(c + 1) & 1];
            #pragma unroll
            for (int i = 0; i < 4; ++i)
                async_cp16(src + i * 4096 + w * 1024 + lane * 16,
                           dst + i * 4096 + w * 1024);
        }
        const unsigned short* buf = ring[c & 1];
        #pragma unroll
        for (int ns = 0; ns < 2; ++ns) {
            const float nv = norms[(h * 64 + c) * 32 + ns * 16 + col];
            bf16x8 bfrag[8];
            #pragma unroll
            for (int ks = 0; ks < 8; ++ks)     // lane-contiguous 1KB: conflict-free
                bfrag[ks] = *(const bf16x8*)&buf[((ns * 8 + ks) * 64 + lane) * 8];
            floatx4 acc0 = (floatx4){nv, nv, nv, nv};
            floatx4 acc1 = (floatx4){nv, nv, nv, nv};
            #pragma unroll
            for (int ks = 0; ks < 8; ++ks) {
                acc0 = __builtin_amdgcn_mfma_f32_16x16x32_bf16(
                           af0[ks], bfrag[ks], acc0, 0, 0, 0);
                acc1 = __builtin_amdgcn_mfma_f32_16x16x32_bf16(
                           af1[ks], bfrag[ks], acc1, 0, 0, 0);
            }
            const unsigned int code = (unsigned int)((h * 64 + c) * 32 + ns * 16 + col);
            #pragma unroll
            for (int r = 0; r < 4; ++r) {
                unsigned int k0 = (__float_as_uint(acc0[r]) & 0xFFFFF000u) | code;
                minkey0[r] = k0 < minkey0[r] ? k0 : minkey0[r];
                unsigned int k1 = (__float_as_uint(acc1[r]) & 0xFFFFF000u) | code;
                minkey1[r] = k1 < minkey1[r] ? k1 : minkey1[r];
            }
        }
    }

    // ---- min over 16 column-lanes, write packed (dist|code) per token.
    // token in block = w*32 + m2*16 + quad*4 + r
    #pragma unroll
    for (int r = 0; r < 4; ++r) {
        unsigned int k = minkey0[r];
        #pragma unroll
        for (int off = 8; off >= 1; off >>= 1) {
            unsigned int o = __shfl_xor(k, off);
            k = o < k ? o : k;
        }
        if (col == 0)
            halfmin[h * NTOK + tb + w * 32 + quad * 4 + r] = k;
        unsigned int k2 = minkey1[r];
        #pragma unroll
        for (int off = 8; off >= 1; off >>= 1) {
            unsigned int o = __shfl_xor(k2, off);
            k2 = o < k2 ? o : k2;
        }
        if (col == 0)
            halfmin[h * NTOK + tb + w * 32 + 16 + quad * 4 + r] = k2;
    }
}

// ---------------- kernel 3: merge + vectorized gather + loss ----------------
// (round-6 verbatim) 256 thr, 128 tokens/block, grid 512. floatx4 loads with
// 128B contiguous codebook segments, static 4x4 register transpose, floatx4
// stores with 128B contiguous output segments.
__global__ __launch_bounds__(256) void k_gather(const float* __restrict__ cb,
        const unsigned int* __restrict__ halfmin, float* __restrict__ out,
        float* __restrict__ loss_slot) {
    __shared__ int sidx[128];
    __shared__ float wp2[2];
    const int t = threadIdx.x;
    const int tb = blockIdx.x * 128;
    const int b = tb >> 11, s0 = tb & 2047;
    if (t < 128) {
        unsigned int k0 = halfmin[tb + t], k1 = halfmin[NTOK + tb + t];
        unsigned int km = k0 < k1 ? k0 : k1;
        sidx[t] = (int)(km & 0xFFFu);
        float dv = __uint_as_float(km & 0xFFFFF000u) - 0.25f;
        #pragma unroll
        for (int off = 1; off < 64; off <<= 1) dv += __shfl_xor(dv, off);
        if ((t & 63) == 0) wp2[t >> 6] = dv;
    }
    __syncthreads();
    if (t == 0) atomicAdd(loss_slot, (wp2[0] + wp2[1]) * (1.25f / 16777216.0f));
    const int q = t >> 3, dg = t & 7;
    int rows[4];
    #pragma unroll
    for (int k = 0; k < 4; ++k) rows[k] = sidx[q * 4 + k];
    float* ob = out + (size_t)b * DIM * SEQ + s0 + q * 4;
    #pragma unroll
    for (int i = 0; i < 8; ++i) {
        const int d0 = i * 32 + dg * 4;
        floatx4 v0 = *(const floatx4*)(cb + (size_t)rows[0] * DIM + d0);
        floatx4 v1 = *(const floatx4*)(cb + (size_t)rows[1] * DIM + d0);
        floatx4 v2 = *(const floatx4*)(cb + (size_t)rows[2] * DIM + d0);
        floatx4 v3 = *(const floatx4*)(cb + (size_t)rows[3] * DIM + d0);
        #pragma unroll
        for (int j = 0; j < 4; ++j) {
            floatx4 o = {v0[j], v1[j], v2[j], v3[j]};
            *(floatx4*)(ob + (size_t)(d0 + j) * SEQ) = o;
        }
    }
}

extern "C" void kernel_launch(void* const* d_in, const int* in_sizes, int n_in,
                              void* d_out, int out_size, void* d_ws, size_t ws_size,
                              hipStream_t stream) {
    const float* inputs   = (const float*)d_in[0];
    const float* codebook = (const float*)d_in[1];
    float* out = (float*)d_out;
    unsigned short* cb_swz = (unsigned short*)d_ws;                                  // 2 MB
    float* norms = (float*)((char*)d_ws + (size_t)K_CODES * DIM * 2);                // 16 KB
    unsigned int* halfmin = (unsigned int*)((char*)d_ws + (size_t)K_CODES * DIM * 2
                                            + K_CODES * 4);                          // 512 KB
    float* loss_slot = out + (out_size - 1);

    hipLaunchKernelGGL(k_prep,   dim3(K_CODES / 32),   dim3(256), 0, stream,
                       codebook, cb_swz, norms, loss_slot);
    hipLaunchKernelGGL(k_argmin, dim3(NTOK / 128 * 2), dim3(256), 0, stream,
                       inputs, cb_swz, norms, halfmin, loss_slot);
    hipLaunchKernelGGL(k_gather, dim3(NTOK / 128),     dim3(256), 0, stream,
                       codebook, halfmin, out, loss_slot);
}

// Round 8
// 237.678 us; speedup vs baseline: 1.0841x; 1.0841x over previous
//
#include <hip/hip_runtime.h>

#define K_CODES 4096
#define DIM 256
#define SEQ 2048
#define NTOK 65536

typedef __bf16 bf16x8 __attribute__((ext_vector_type(8)));
typedef float floatx4 __attribute__((ext_vector_type(4)));
typedef unsigned short u16x8 __attribute__((ext_vector_type(8)));

__device__ __forceinline__ unsigned short f2bf(float f) {
    union { float f; unsigned int u; } v; v.f = f;
    unsigned int u = v.u;
    unsigned int r = u + 0x7fffu + ((u >> 16) & 1u);   // RNE
    return (unsigned short)(r >> 16);
}

// async global->LDS, 16B per lane. LDS dest = wave-uniform base + lane*16.
__device__ __forceinline__ void async_cp16(const void* g, const void* lds_base) {
    typedef __attribute__((address_space(1))) const unsigned int guint;
    typedef __attribute__((address_space(3))) unsigned int luint;
    __builtin_amdgcn_global_load_lds(
        (guint*)(unsigned long long)g,
        (luint*)(unsigned int)(unsigned long long)lds_base,
        16, 0, 0);
}

// ---------------- kernel 1: swizzled bf16 codebook + biased norms -----------
// (round-6 verbatim)
// cb_swz[((gc*16 + ns*8 + ks)*64 + quad*16 + col)*8 + j]
//   = bf16(codebook[gc*32 + ns*16 + col][quad*8 + ks*32 + j])
// norms[row] = ||e||^2 + 0.25 (bias keeps dist positive for the packed key).
__global__ __launch_bounds__(256) void k_prep(const float* __restrict__ cb,
        unsigned short* __restrict__ cb_swz, float* __restrict__ norms,
        float* __restrict__ loss_slot) {
    const int c = blockIdx.x;
    const int t = threadIdx.x;
    const int row_loc = t >> 3;       // 0..31 code within chunk
    const int ks = t & 7;             // k-slice
    const int row = c * 32 + row_loc;
    const float* src = cb + (size_t)row * DIM + ks * 32;
    float vals[32];
    float s = 0.0f;
    #pragma unroll
    for (int i = 0; i < 8; ++i) {
        floatx4 v = *(const floatx4*)(src + i * 4);
        #pragma unroll
        for (int j = 0; j < 4; ++j) { vals[i * 4 + j] = v[j]; s += v[j] * v[j]; }
    }
    const int ns = row_loc >> 4, col = row_loc & 15;
    #pragma unroll
    for (int quad = 0; quad < 4; ++quad) {
        u16x8 p;
        #pragma unroll
        for (int j = 0; j < 8; ++j) p[j] = f2bf(vals[quad * 8 + j]);
        *(u16x8*)(cb_swz + ((size_t)((c * 16 + ns * 8 + ks) * 64 + quad * 16 + col)) * 8) = p;
    }
    s += __shfl_xor(s, 1); s += __shfl_xor(s, 2); s += __shfl_xor(s, 4);
    if (ks == 0) norms[row] = s + 0.25f;
    if (c == 0 && t == 0) *loss_slot = 0.0f;
}

// ---------------- kernel 2: MFMA distance GEMM + packed argmin --------------
// Round-6 shape (256 tok/block, 4 waves, af[4][8], 2 blocks/CU) with 64-CODE
// CHUNKS: ring = 2 x 32KB, 32 barriers instead of 64, 128 MFMA/wave/barrier
// (round-7 showed per-barrier overhead, not occupancy, is the limiter; this
// halves barrier count at constant total MFMA). xs (64 tok x stride-256 +
// round-7-verified XOR swizzle = exactly 32KB) aliases ring1, first written
// by the chunk-1 prefetch after xs is dead. Fragment capture = round-6's
// static af[m][ks] structure; address adds swizzle key (m*4 + col>>2)&7,
// matching the staging key (tok>>2)&7.
__global__ __launch_bounds__(256, 2) void k_argmin(const float* __restrict__ x,
        const unsigned short* __restrict__ cb_swz, const float* __restrict__ norms,
        unsigned int* __restrict__ halfmin, float* __restrict__ loss_slot) {
    __shared__ __align__(16) unsigned short ring0[16384];   // 32768 B
    __shared__ __align__(16) unsigned short ring1[16384];   // 32768 B
    __shared__ float wpart[4];
    unsigned short* xs = ring1;          // prologue-only alias: 64 tok x 256 d
    const int t = threadIdx.x;
    const int lane = t & 63, w = t >> 6;
    const int col = lane & 15, quad = lane >> 4;
    const int bx = blockIdx.x;
    const int h = bx & 1;                  // code half
    const int tb = (bx >> 1) * 256;        // first token of block
    const int b = tb >> 11, s0 = tb & 2047;
    const float* xin = x + (size_t)b * DIM * SEQ;

    // prefetch B chunk 0 (64 codes, 32KB) of this half into ring0
    {
        const char* src = (const char*)cb_swz + (size_t)h * 1048576;
        #pragma unroll
        for (int i = 0; i < 8; ++i)
            async_cp16(src + i * 4096 + w * 1024 + lane * 16,
                       (char*)ring0 + i * 4096 + w * 1024);
    }

    // ---- X staging: 4 phases x 64 tokens into xs(=ring1); wave ph grabs its
    // A fragments in phase ph. Element (tok,d) at
    //   xs[tok*256 + ((d>>3) ^ ((tok>>2)&7))*8 + (d&7)]   (XOR swizzle)
    bf16x8 af[4][8];
    float a2 = 0.0f;
    const int dg = t >> 4, sq = (t & 15) * 4, key = t & 7;   // key = (tok>>2)&7
    for (int ph = 0; ph < 4; ++ph) {
        const int sbase = s0 + ph * 64 + sq;
        #pragma unroll
        for (int i = 0; i < 16; ++i) {
            const int d = i * 16 + dg;
            floatx4 v = *(const floatx4*)(xin + (size_t)d * SEQ + sbase);
            a2 += v[0]*v[0] + v[1]*v[1] + v[2]*v[2] + v[3]*v[3];
            const int chs = (d >> 3) ^ key;          // swizzled 16B chunk
            #pragma unroll
            for (int j = 0; j < 4; ++j)
                xs[(sq + j) * 256 + chs * 8 + (d & 7)] = f2bf(-2.0f * v[j]);
        }
        __syncthreads();
        if (w == ph) {
            #pragma unroll
            for (int m = 0; m < 4; ++m) {
                const int rk = (m * 4 + (col >> 2)) & 7;   // row swizzle key
                #pragma unroll
                for (int ks = 0; ks < 8; ++ks)
                    af[m][ks] = *(const bf16x8*)
                        &xs[(m * 16 + col) * 256 + ((quad + ks * 4) ^ rk) * 8];
            }
        }
        __syncthreads();
    }
    // block-reduce a2; h==0 blocks contribute ||x||^2 part of the loss
    #pragma unroll
    for (int off = 1; off < 64; off <<= 1) a2 += __shfl_xor(a2, off);
    if (lane == 0) wpart[w] = a2;
    __syncthreads();   // xs dead from here; ring1 free for chunk-1 prefetch
    if (t == 0 && h == 0)
        atomicAdd(loss_slot,
                  (wpart[0] + wpart[1] + wpart[2] + wpart[3]) * (1.25f / 16777216.0f));

    unsigned int minkey[4][4];
    #pragma unroll
    for (int m = 0; m < 4; ++m)
        #pragma unroll
        for (int r = 0; r < 4; ++r) minkey[m][r] = 0xFFFFFFFFu;

    #pragma unroll 1
    for (int cc = 0; cc < 32; ++cc) {
        __syncthreads();                 // ring[cc&1] ready, readers of cc-1 done
        if (cc < 31) {
            const char* src = (const char*)cb_swz + (size_t)h * 1048576
                              + (size_t)(cc + 1) * 32768;
            char* dst = (char*)(((cc + 1) & 1) ? ring1 : ring0);
            #pragma unroll
            for (int i = 0; i < 8; ++i)
                async_cp16(src + i * 4096 + w * 1024 + lane * 16,
                           dst + i * 4096 + w * 1024);
        }
        const unsigned short* buf = (cc & 1) ? ring1 : ring0;
        #pragma unroll
        for (int ns = 0; ns < 4; ++ns) {   // 4 x 16 codes (two gc-blocks, contiguous)
            const float nv = norms[h * 2048 + cc * 64 + ns * 16 + col];
            bf16x8 bfrag[8];
            #pragma unroll
            for (int ks = 0; ks < 8; ++ks)   // lane-contiguous 1KB: conflict-free
                bfrag[ks] = *(const bf16x8*)&buf[((ns * 8 + ks) * 64 + lane) * 8];
            floatx4 acc[4];
            #pragma unroll
            for (int m = 0; m < 4; ++m) acc[m] = (floatx4){nv, nv, nv, nv};
            #pragma unroll
            for (int ks = 0; ks < 8; ++ks)
                #pragma unroll
                for (int m = 0; m < 4; ++m)
                    acc[m] = __builtin_amdgcn_mfma_f32_16x16x32_bf16(
                                 af[m][ks], bfrag[ks], acc[m], 0, 0, 0);
            const unsigned int code = (unsigned int)(h * 2048 + cc * 64 + ns * 16 + col);
            #pragma unroll
            for (int m = 0; m < 4; ++m)
                #pragma unroll
                for (int r = 0; r < 4; ++r) {
                    unsigned int kk = (__float_as_uint(acc[m][r]) & 0xFFFFF000u) | code;
                    minkey[m][r] = kk < minkey[m][r] ? kk : minkey[m][r];
                }
        }
    }

    // ---- min over 16 column-lanes, write packed (dist|code) per token
    #pragma unroll
    for (int m = 0; m < 4; ++m)
        #pragma unroll
        for (int r = 0; r < 4; ++r) {
            unsigned int k = minkey[m][r];
            #pragma unroll
            for (int off = 8; off >= 1; off >>= 1) {
                unsigned int o = __shfl_xor(k, off);
                k = o < k ? o : k;
            }
            if (col == 0)
                halfmin[h * NTOK + tb + w * 64 + m * 16 + quad * 4 + r] = k;
        }
}

// ---------------- kernel 3: merge + vectorized gather + loss ----------------
// (round-6 verbatim) 256 thr, 128 tokens/block, grid 512. floatx4 loads with
// 128B contiguous codebook segments, static 4x4 register transpose, floatx4
// stores with 128B contiguous output segments.
__global__ __launch_bounds__(256) void k_gather(const float* __restrict__ cb,
        const unsigned int* __restrict__ halfmin, float* __restrict__ out,
        float* __restrict__ loss_slot) {
    __shared__ int sidx[128];
    __shared__ float wp2[2];
    const int t = threadIdx.x;
    const int tb = blockIdx.x * 128;
    const int b = tb >> 11, s0 = tb & 2047;
    if (t < 128) {
        unsigned int k0 = halfmin[tb + t], k1 = halfmin[NTOK + tb + t];
        unsigned int km = k0 < k1 ? k0 : k1;
        sidx[t] = (int)(km & 0xFFFu);
        float dv = __uint_as_float(km & 0xFFFFF000u) - 0.25f;
        #pragma unroll
        for (int off = 1; off < 64; off <<= 1) dv += __shfl_xor(dv, off);
        if ((t & 63) == 0) wp2[t >> 6] = dv;
    }
    __syncthreads();
    if (t == 0) atomicAdd(loss_slot, (wp2[0] + wp2[1]) * (1.25f / 16777216.0f));
    const int q = t >> 3, dg = t & 7;
    int rows[4];
    #pragma unroll
    for (int k = 0; k < 4; ++k) rows[k] = sidx[q * 4 + k];
    float* ob = out + (size_t)b * DIM * SEQ + s0 + q * 4;
    #pragma unroll
    for (int i = 0; i < 8; ++i) {
        const int d0 = i * 32 + dg * 4;
        floatx4 v0 = *(const floatx4*)(cb + (size_t)rows[0] * DIM + d0);
        floatx4 v1 = *(const floatx4*)(cb + (size_t)rows[1] * DIM + d0);
        floatx4 v2 = *(const floatx4*)(cb + (size_t)rows[2] * DIM + d0);
        floatx4 v3 = *(const floatx4*)(cb + (size_t)rows[3] * DIM + d0);
        #pragma unroll
        for (int j = 0; j < 4; ++j) {
            floatx4 o = {v0[j], v1[j], v2[j], v3[j]};
            *(floatx4*)(ob + (size_t)(d0 + j) * SEQ) = o;
        }
    }
}

extern "C" void kernel_launch(void* const* d_in, const int* in_sizes, int n_in,
                              void* d_out, int out_size, void* d_ws, size_t ws_size,
                              hipStream_t stream) {
    const float* inputs   = (const float*)d_in[0];
    const float* codebook = (const float*)d_in[1];
    float* out = (float*)d_out;
    unsigned short* cb_swz = (unsigned short*)d_ws;                                  // 2 MB
    float* norms = (float*)((char*)d_ws + (size_t)K_CODES * DIM * 2);                // 16 KB
    unsigned int* halfmin = (unsigned int*)((char*)d_ws + (size_t)K_CODES * DIM * 2
                                            + K_CODES * 4);                          // 512 KB
    float* loss_slot = out + (out_size - 1);

    hipLaunchKernelGGL(k_prep,   dim3(K_CODES / 32),   dim3(256), 0, stream,
                       codebook, cb_swz, norms, loss_slot);
    hipLaunchKernelGGL(k_argmin, dim3(NTOK / 256 * 2), dim3(256), 0, stream,
                       inputs, cb_swz, norms, halfmin, loss_slot);
    hipLaunchKernelGGL(k_gather, dim3(NTOK / 128),     dim3(256), 0, stream,
                       codebook, halfmin, out, loss_slot);
}